// Round 8
// baseline (535.688 us; speedup 1.0000x reference)
//
#include <hip/hip_runtime.h>
#include <hip/hip_bf16.h>
#include <stdint.h>

#define N_NODES 100000
#define N_EDGES 1600000
#define D_FEAT 32
#define CUT_K 320000        // int(N_EDGES * 0.2)
#define COSKEY_NB 3125      // 2 edges/thread: 3125*256*2 == N_EDGES exactly
#define HC_NB 1000          // histc blocks; E = HC_NB * HC_SLICE exactly
#define HC_SLICE 1600
#define SCAN_NB ((N_NODES + 255) / 256)   // 391
#define TAILCAP 400000      // tail scratch slots per ping-pong half

// packed CSR record: [54:38]=src (17b) | [37:21]=dst (17b) | [20:0]=eid (21b)
#define PK(s, d, e) ((((unsigned long long)(s)) << 38) | \
                     (((unsigned long long)(d)) << 21) | (unsigned long long)(e))
#define PK_SRC(p) ((unsigned int)((p) >> 38))
#define PK_DST(p) ((unsigned int)(((p) >> 21) & 0x1FFFFu))
#define PK_EID(p) ((unsigned int)((p) & 0x1FFFFFu))

struct SelState { unsigned long long prefix; unsigned int k; };

// count in-degrees AND capture each edge's rank within its dst segment
// (the atomicAdd return value). rank[e] is coalesced; fill is atomic-free.
__global__ void deg_kernel(const int* __restrict__ dst, int* __restrict__ deg,
                           int* __restrict__ rank, int E) {
    int e = blockIdx.x * blockDim.x + threadIdx.x;
    if (e < E) rank[e] = atomicAdd(&deg[dst[e]], 1);
}

// per-256-chunk sums of deg; nrm fused (reads deg anyway)
__global__ void blocksum_kernel(const int* __restrict__ deg, int* __restrict__ bsum,
                                float* __restrict__ nrm, int N) {
    int i = blockIdx.x * 256 + threadIdx.x;
    int v = (i < N) ? deg[i] : 0;
    if (i < N) nrm[i] = 1.0f / sqrtf(fmaxf((float)v, 1.0f));
#pragma unroll
    for (int off = 32; off > 0; off >>= 1) v += __shfl_down(v, off, 64);
    __shared__ int ws4[4];
    if ((threadIdx.x & 63) == 0) ws4[threadIdx.x >> 6] = v;
    __syncthreads();
    if (threadIdx.x == 0) bsum[blockIdx.x] = ws4[0] + ws4[1] + ws4[2] + ws4[3];
}

// writeoffs with the block-offset reduction folded in: each block redundantly
// sums bsum[0..blockIdx) (<=391 ints, L2-hot) — removes the scanpartial launch.
__global__ void writeoffs_kernel(const int* __restrict__ deg, const int* __restrict__ bsum,
                                 int* __restrict__ offs, int N) {
    __shared__ int buf[256];
    __shared__ int ws4[4];
    __shared__ int sboff;
    int t = threadIdx.x;
    int b = blockIdx.x;
    int partial = 0;
    for (int i = t; i < b; i += 256) partial += bsum[i];
#pragma unroll
    for (int off = 32; off > 0; off >>= 1) partial += __shfl_down(partial, off, 64);
    if ((t & 63) == 0) ws4[t >> 6] = partial;
    __syncthreads();
    if (t == 0) sboff = ws4[0] + ws4[1] + ws4[2] + ws4[3];
    __syncthreads();
    int i = b * 256 + t;
    int v = (i < N) ? deg[i] : 0;
    buf[t] = v;
    __syncthreads();
    for (int off = 1; off < 256; off <<= 1) {
        int u = (t >= off) ? buf[t - off] : 0;
        __syncthreads();
        buf[t] += u;
        __syncthreads();
    }
    int ex = buf[t] - v + sboff;
    if (i < N) offs[i] = ex;
    if (i == N - 1) offs[N] = ex + v;   // == E
}

// ATOMIC-FREE scatter into CSR-by-dst slots: pos = offs[dst] + rank.
// One packed 8B record per edge (halves every downstream csr read stream).
__global__ void fill_kernel(const int* __restrict__ src, const int* __restrict__ dst,
                            const int* __restrict__ rank, const int* __restrict__ offs,
                            unsigned long long* __restrict__ csr8, int E) {
    int e = blockIdx.x * blockDim.x + threadIdx.x;
    if (e >= E) return;
    int d = dst[e];
    int pos = offs[d] + rank[e];
    csr8[pos] = PK((unsigned int)src[e], (unsigned int)d, (unsigned int)e);
}

// Redundant per-block 256-bin scan/select (reads the PREVIOUS kernel's
// histogram — visible via stream ordering, no fences). All 256 threads.
__device__ __forceinline__ unsigned long long scan_select(
        const unsigned int* __restrict__ hist,
        unsigned long long pfx_in, unsigned int k_in,
        unsigned int* k_out) {
    __shared__ unsigned int sbuf[256];
    __shared__ unsigned long long s_pfx;
    __shared__ unsigned int s_k;
    int t = threadIdx.x;
    unsigned int s = hist[t];
    sbuf[t] = s;
    __syncthreads();
    for (int off = 1; off < 256; off <<= 1) {
        unsigned int v = (t >= off) ? sbuf[t - off] : 0u;
        __syncthreads();
        sbuf[t] += v;
        __syncthreads();
    }
    unsigned int incl = sbuf[t];
    unsigned int excl = incl - s;
    if (excl < k_in && k_in <= incl) {          // exactly one thread wins
        s_pfx = (pfx_in << 8) | (unsigned long long)t;
        s_k = k_in - excl;
    }
    __syncthreads();
    if (k_out) *k_out = s_k;
    return s_pfx;
}

// edge-parallel cos keys with FUSED normalization (rownorm kernel deleted).
// Per row: pass 1 computes ss with the EXACT accumulation order of the old
// rownorm (per-q x*x+y*y+z*z+w*w); inv = 1/max(sqrt(ss),1e-12) identical;
// pass 2 re-reads the row (L1-hot) and forms na = xa*inv (same individually-
// rounded mul the old nh store produced) then the same dot expression shape
// -> bit-identical cos keys. 2 consecutive edges/thread for gather MLP.
__global__ void coskey_kernel(const float* __restrict__ h,
                              const unsigned long long* __restrict__ csr8,
                              unsigned long long* __restrict__ keys,
                              unsigned int* __restrict__ hist0, int E) {
    __shared__ unsigned int lh[4][256];
    int t = threadIdx.x;
#pragma unroll
    for (int w = 0; w < 4; ++w) lh[w][t] = 0u;
    __syncthreads();
    int wave = t >> 6;
    int p0 = (blockIdx.x * 256 + t) * 2;      // p0+1 < E by construction
    unsigned long long r0 = csr8[p0];
    unsigned long long r1 = csr8[p0 + 1];
    const float4* a0 = (const float4*)(h + (size_t)PK_SRC(r0) * D_FEAT);
    const float4* b0 = (const float4*)(h + (size_t)PK_DST(r0) * D_FEAT);
    const float4* a1 = (const float4*)(h + (size_t)PK_SRC(r1) * D_FEAT);
    const float4* b1 = (const float4*)(h + (size_t)PK_DST(r1) * D_FEAT);
    float sa0 = 0.f, sb0 = 0.f, sa1 = 0.f, sb1 = 0.f;
#pragma unroll
    for (int q = 0; q < 8; ++q) {
        float4 x = a0[q]; sa0 += x.x * x.x + x.y * x.y + x.z * x.z + x.w * x.w;
        float4 y = b0[q]; sb0 += y.x * y.x + y.y * y.y + y.z * y.z + y.w * y.w;
        float4 z = a1[q]; sa1 += z.x * z.x + z.y * z.y + z.z * z.z + z.w * z.w;
        float4 w4 = b1[q]; sb1 += w4.x * w4.x + w4.y * w4.y + w4.z * w4.z + w4.w * w4.w;
    }
    float ia0 = 1.0f / fmaxf(sqrtf(sa0), 1e-12f);
    float ib0 = 1.0f / fmaxf(sqrtf(sb0), 1e-12f);
    float ia1 = 1.0f / fmaxf(sqrtf(sa1), 1e-12f);
    float ib1 = 1.0f / fmaxf(sqrtf(sb1), 1e-12f);
    float s0 = 0.f, s1 = 0.f;
#pragma unroll
    for (int q = 0; q < 8; ++q) {
        float4 xa = a0[q], xb = b0[q];
        float4 na, nb;
        na.x = xa.x * ia0; na.y = xa.y * ia0; na.z = xa.z * ia0; na.w = xa.w * ia0;
        nb.x = xb.x * ib0; nb.y = xb.y * ib0; nb.z = xb.z * ib0; nb.w = xb.w * ib0;
        s0 += na.x * nb.x + na.y * nb.y + na.z * nb.z + na.w * nb.w;
        float4 ya = a1[q], yb = b1[q];
        float4 ma, mb;
        ma.x = ya.x * ia1; ma.y = ya.y * ia1; ma.z = ya.z * ia1; ma.w = ya.w * ia1;
        mb.x = yb.x * ib1; mb.y = yb.y * ib1; mb.z = yb.z * ib1; mb.w = yb.w * ib1;
        s1 += ma.x * mb.x + ma.y * mb.y + ma.z * mb.z + ma.w * mb.w;
    }
    unsigned int u0 = __float_as_uint(s0);
    unsigned int so0 = (u0 & 0x80000000u) ? ~u0 : (u0 | 0x80000000u);
    unsigned long long k0 = ((unsigned long long)so0 << 32) | PK_EID(r0);
    unsigned int u1 = __float_as_uint(s1);
    unsigned int so1 = (u1 & 0x80000000u) ? ~u1 : (u1 | 0x80000000u);
    unsigned long long k1 = ((unsigned long long)so1 << 32) | PK_EID(r1);
    *(ulonglong2*)(keys + p0) = make_ulonglong2(k0, k1);
    atomicAdd(&lh[wave][(unsigned int)(k0 >> 56)], 1u);
    atomicAdd(&lh[wave][(unsigned int)(k1 >> 56)], 1u);
    __syncthreads();
    unsigned int tot = lh[0][t] + lh[1][t] + lh[2][t] + lh[3][t];
    if (tot) atomicAdd(&hist0[t], tot);
}

// compacting radix pass p (1..2). Redundant scan of hist_prev derives
// (prefix,k); block 0 persists it to st_out (read only by later kernels).
__global__ void histc_kernel(const unsigned long long* __restrict__ in,
                             const int* __restrict__ cnt_in,      // null => dense (pass 1)
                             unsigned long long* __restrict__ out,
                             int* __restrict__ cnt_out,
                             const SelState* __restrict__ st_in,  // null => {0, CUT_K}
                             SelState* __restrict__ st_out,
                             const unsigned int* __restrict__ hist_prev,
                             unsigned int* __restrict__ hist_cur, int pass) {
    __shared__ unsigned int lh[4][256];
    __shared__ unsigned int lcnt;
    int t = threadIdx.x, b = blockIdx.x;
#pragma unroll
    for (int w = 0; w < 4; ++w) lh[w][t] = 0u;
    if (t == 0) lcnt = 0u;

    unsigned long long pfx_in = st_in ? st_in->prefix : 0ull;
    unsigned int k_in = st_in ? st_in->k : (unsigned int)CUT_K;
    unsigned int k_cur;
    unsigned long long prefix = scan_select(hist_prev, pfx_in, k_in, &k_cur);
    if (b == 0 && t == 0) { st_out->prefix = prefix; st_out->k = k_cur; }
    __syncthreads();

    int n = cnt_in ? cnt_in[b] : HC_SLICE;
    const unsigned long long* sin = in + (size_t)b * HC_SLICE;
    unsigned long long* sout = out + (size_t)b * HC_SLICE;
    int wave = t >> 6;
    int fshift = 64 - 8 * pass;
    int dshift = 56 - 8 * pass;
    for (int i = t; i < n; i += 256) {
        unsigned long long key = sin[i];
        if ((key >> fshift) == prefix) {
            atomicAdd(&lh[wave][(unsigned int)((key >> dshift) & 0xFFull)], 1u);
            unsigned int slot = atomicAdd(&lcnt, 1u);   // LDS atomic, block-local
            sout[slot] = key;
        }
    }
    __syncthreads();
    if (t == 0) cnt_out[b] = (int)lcnt;
    unsigned int tot = lh[0][t] + lh[1][t] + lh[2][t] + lh[3][t];
    if (tot) atomicAdd(&hist_cur[t], tot);
}

// single-block tail: radix passes 3..7 + final select, one launch.
__global__ void tail_kernel(const unsigned long long* __restrict__ in_sl,
                            const int* __restrict__ cnt_in,
                            unsigned long long* __restrict__ dense,
                            const SelState* __restrict__ st2,
                            const unsigned int* __restrict__ hist2,
                            unsigned long long* __restrict__ kth_out) {
    __shared__ unsigned int lh[256];
    __shared__ unsigned int sbuf[256];
    __shared__ unsigned long long s_pfx;
    __shared__ unsigned int s_k;
    __shared__ unsigned int s_n;
    int t = threadIdx.x;

    unsigned long long pfx = st2->prefix;
    unsigned int k = st2->k;
    {   // select digit 2 from hist2 (global, written by pass 2)
        unsigned int s = hist2[t];
        sbuf[t] = s;
        __syncthreads();
        for (int off = 1; off < 256; off <<= 1) {
            unsigned int v = (t >= off) ? sbuf[t - off] : 0u;
            __syncthreads();
            sbuf[t] += v;
            __syncthreads();
        }
        unsigned int incl = sbuf[t], excl = incl - s;
        if (excl < k && k <= incl) { s_pfx = (pfx << 8) | (unsigned long long)t; s_k = k - excl; }
        __syncthreads();
        pfx = s_pfx; k = s_k;
        __syncthreads();
    }

    unsigned int n_in = 0;
    for (int pass = 3; pass < 8; ++pass) {
        lh[t] = 0u;
        if (t == 0) s_n = 0u;
        __syncthreads();
        int fshift = 64 - 8 * pass;
        int dshift = 56 - 8 * pass;
        unsigned long long* outp = dense + ((pass & 1) ? 0 : TAILCAP);
        if (pass == 3) {
            for (int b = t; b < HC_NB; b += 256) {
                int n = cnt_in[b];
                const unsigned long long* sl = in_sl + (size_t)b * HC_SLICE;
                for (int i = 0; i < n; ++i) {
                    unsigned long long key = sl[i];
                    if ((key >> fshift) == pfx) {
                        atomicAdd(&lh[(unsigned int)((key >> dshift) & 0xFFull)], 1u);
                        unsigned int slot = atomicAdd(&s_n, 1u);
                        if (slot < TAILCAP) outp[slot] = key;
                    }
                }
            }
        } else {
            const unsigned long long* inp = dense + ((pass & 1) ? TAILCAP : 0);
            for (unsigned int i = t; i < n_in; i += 256) {
                unsigned long long key = inp[i];
                if ((key >> fshift) == pfx) {
                    atomicAdd(&lh[(unsigned int)((key >> dshift) & 0xFFull)], 1u);
                    unsigned int slot = atomicAdd(&s_n, 1u);
                    if (slot < TAILCAP) outp[slot] = key;
                }
            }
        }
        __syncthreads();
        n_in = s_n;
        unsigned int s = lh[t];
        sbuf[t] = s;
        __syncthreads();
        for (int off = 1; off < 256; off <<= 1) {
            unsigned int v = (t >= off) ? sbuf[t - off] : 0u;
            __syncthreads();
            sbuf[t] += v;
            __syncthreads();
        }
        unsigned int incl = sbuf[t], excl = incl - s;
        if (excl < k && k <= incl) { s_pfx = (pfx << 8) | (unsigned long long)t; s_k = k - excl; }
        __syncthreads();
        pfx = s_pfx; k = s_k;
        __syncthreads();
    }
    if (t == 0) *kth_out = pfx;    // full 64-bit kth key
}

// pull aggregation: one 32-lane group per node walks its CSR segment.
// Gathers RAW h * nrm[src] inline (bit-identical to staged form). Reads the
// packed 8B csr record (src via shift). FUSE_FC: hop-2 applies W via LDS.
template<bool FUSE_FC>
__global__ void aggregate_csr_kernel(const float* __restrict__ h_in, float* __restrict__ h_out,
                                     const int* __restrict__ offs,
                                     const unsigned long long* __restrict__ csr8,
                                     const unsigned long long* __restrict__ keys,
                                     const unsigned long long* __restrict__ kth_in,
                                     const float* __restrict__ nrm,
                                     const float* __restrict__ W, int N) {
    __shared__ float Ws[32][33];
    __shared__ float hrow[8][33];
    int t = threadIdx.x;
    if (FUSE_FC) {
        for (int i = t; i < 1024; i += 256) Ws[i >> 5][i & 31] = W[i];  // Ws[o][j]
        __syncthreads();
    }
    unsigned long long kth = *kth_in;
    int g = blockIdx.x * 8 + (t >> 5);
    int j = t & 31;
    if (!FUSE_FC && g >= N) return;    // grid is exact; guard kept for safety
    int lo = offs[g], hi = offs[g + 1];
    float acc = 0.f;
    int p = lo;
    for (; p + 8 <= hi; p += 8) {
        unsigned long long kk[8];
        unsigned int ss[8];
#pragma unroll
        for (int u = 0; u < 8; ++u) { kk[u] = keys[p + u]; ss[u] = PK_SRC(csr8[p + u]); }
        float vv[8];
#pragma unroll
        for (int u = 0; u < 8; ++u) vv[u] = h_in[(size_t)ss[u] * D_FEAT + j] * nrm[ss[u]];
#pragma unroll
        for (int u = 0; u < 8; ++u) acc += (kk[u] > kth) ? vv[u] : 0.f;  // same seq FP order
    }
    for (; p < hi; ++p) {
        if (keys[p] > kth) {
            unsigned int s = PK_SRC(csr8[p]);
            acc += h_in[(size_t)s * D_FEAT + j] * nrm[s];
        }
    }
    float val = acc * nrm[g];
    if (!FUSE_FC) {
        h_out[(size_t)g * D_FEAT + j] = val;
        return;
    }
    hrow[t >> 5][j] = val;
    __syncthreads();
    float oacc = 0.f;
#pragma unroll
    for (int q = 0; q < 32; ++q) oacc += hrow[t >> 5][q] * Ws[j][q];   // lane j == out feat
    h_out[(size_t)g * D_FEAT + j] = oacc;
}

extern "C" void kernel_launch(void* const* d_in, const int* in_sizes, int n_in,
                              void* d_out, int out_size, void* d_ws, size_t ws_size,
                              hipStream_t stream) {
    const float* features = (const float*)d_in[0];
    const float* W        = (const float*)d_in[1];
    const int*   src      = (const int*)d_in[2];
    const int*   dst      = (const int*)d_in[3];
    float*       out      = (float*)d_out;

    char* ws = (char*)d_ws;
    size_t o = 0;
    auto take = [&](size_t bytes) -> char* {
        char* p = ws + o;
        o += (bytes + 255) & ~(size_t)255;
        return p;
    };
    int*                deg     = (int*)take((size_t)N_NODES * 4);
    float*              nrm     = (float*)take((size_t)N_NODES * 4);
    int*                offs    = (int*)take((size_t)(N_NODES + 1) * 4);
    int*                rank    = (int*)take((size_t)N_EDGES * 4);
    unsigned long long* csr8    = (unsigned long long*)take((size_t)N_EDGES * 8);
    float*              hA      = (float*)take((size_t)N_NODES * D_FEAT * 4);
    unsigned long long* keys    = (unsigned long long*)take((size_t)N_EDGES * 8);
    unsigned long long* candA   = (unsigned long long*)take((size_t)HC_NB * HC_SLICE * 8);
    unsigned long long* candB   = (unsigned long long*)take((size_t)HC_NB * HC_SLICE * 8);
    unsigned int*       hist    = (unsigned int*)take((size_t)16 * 256 * 4); // per-pass bins
    SelState*           stArr   = (SelState*)take((size_t)16 * sizeof(SelState));
    unsigned long long* kthbuf  = (unsigned long long*)take(256);
    int*                bsum    = (int*)take((size_t)SCAN_NB * 4);
    int*                cnt_a   = (int*)take((size_t)HC_NB * 4);
    int*                cnt_b   = (int*)take((size_t)HC_NB * 4);

    hipMemsetAsync(deg, 0, (size_t)N_NODES * 4, stream);
    hipMemsetAsync(hist, 0, (size_t)16 * 256 * 4, stream);

    deg_kernel<<<(N_EDGES + 255) / 256, 256, 0, stream>>>(dst, deg, rank, N_EDGES);
    blocksum_kernel<<<SCAN_NB, 256, 0, stream>>>(deg, bsum, nrm, N_NODES);
    writeoffs_kernel<<<SCAN_NB, 256, 0, stream>>>(deg, bsum, offs, N_NODES);
    fill_kernel<<<(N_EDGES + 255) / 256, 256, 0, stream>>>(src, dst, rank, offs, csr8, N_EDGES);

    const float* hin = features;
    for (int hop = 0; hop < 2; ++hop) {
        unsigned int* hh = hist + (size_t)hop * 8 * 256;   // per-pass histograms
        SelState*     hst = stArr + (size_t)hop * 8;       // slots [1..2] used
        coskey_kernel<<<COSKEY_NB, 256, 0, stream>>>(hin, csr8, keys, hh, N_EDGES);
        // pass 1: dense keys -> candA slices
        histc_kernel<<<HC_NB, 256, 0, stream>>>(keys, nullptr, candA, cnt_a,
                                                nullptr, hst + 1,
                                                hh + 0 * 256, hh + 1 * 256, 1);
        // pass 2: candA slices -> candB slices
        histc_kernel<<<HC_NB, 256, 0, stream>>>(candA, cnt_a, candB, cnt_b,
                                                hst + 1, hst + 2,
                                                hh + 1 * 256, hh + 2 * 256, 2);
        // passes 3..7 + final select in ONE single-block launch
        tail_kernel<<<1, 256, 0, stream>>>(candB, cnt_b, candA,
                                           hst + 2, hh + 2 * 256, kthbuf + hop);
        if (hop == 0) {
            aggregate_csr_kernel<false><<<(N_NODES + 7) / 8, 256, 0, stream>>>(
                hin, hA, offs, csr8, keys, kthbuf + hop, nrm, nullptr, N_NODES);
            hin = hA;
        } else {
            aggregate_csr_kernel<true><<<(N_NODES + 7) / 8, 256, 0, stream>>>(
                hin, out, offs, csr8, keys, kthbuf + hop, nrm, W, N_NODES);
        }
    }
}

// Round 9
// 509.070 us; speedup vs baseline: 1.0523x; 1.0523x over previous
//
#include <hip/hip_runtime.h>
#include <hip/hip_bf16.h>
#include <stdint.h>

#define N_NODES 100000
#define N_EDGES 1600000
#define D_FEAT 32
#define CUT_K 320000        // int(N_EDGES * 0.2)
#define COSKEY_NB 3125      // 2 edges/thread: 3125*256*2 == N_EDGES exactly
#define HC_NB 1000          // histc blocks; E = HC_NB * HC_SLICE exactly
#define HC_SLICE 1600
#define SCAN_NB ((N_NODES + 255) / 256)   // 391
#define TAILCAP 400000      // tail scratch slots per ping-pong half

// packed CSR record: [54:38]=src (17b) | [37:21]=dst (17b) | [20:0]=eid (21b)
#define PK(s, d, e) ((((unsigned long long)(s)) << 38) | \
                     (((unsigned long long)(d)) << 21) | (unsigned long long)(e))
#define PK_SRC(p) ((unsigned int)((p) >> 38))
#define PK_DST(p) ((unsigned int)(((p) >> 21) & 0x1FFFFu))
#define PK_EID(p) ((unsigned int)((p) & 0x1FFFFFu))

struct SelState { unsigned long long prefix; unsigned int k; };

// count in-degrees AND capture each edge's rank within its dst segment
// (the atomicAdd return value). rank[e] is coalesced; fill is atomic-free.
__global__ void deg_kernel(const int* __restrict__ dst, int* __restrict__ deg,
                           int* __restrict__ rank, int E) {
    int e = blockIdx.x * blockDim.x + threadIdx.x;
    if (e < E) rank[e] = atomicAdd(&deg[dst[e]], 1);
}

// per-256-chunk sums of deg; nrm fused (reads deg anyway)
__global__ void blocksum_kernel(const int* __restrict__ deg, int* __restrict__ bsum,
                                float* __restrict__ nrm, int N) {
    int i = blockIdx.x * 256 + threadIdx.x;
    int v = (i < N) ? deg[i] : 0;
    if (i < N) nrm[i] = 1.0f / sqrtf(fmaxf((float)v, 1.0f));
#pragma unroll
    for (int off = 32; off > 0; off >>= 1) v += __shfl_down(v, off, 64);
    __shared__ int ws4[4];
    if ((threadIdx.x & 63) == 0) ws4[threadIdx.x >> 6] = v;
    __syncthreads();
    if (threadIdx.x == 0) bsum[blockIdx.x] = ws4[0] + ws4[1] + ws4[2] + ws4[3];
}

// writeoffs with the block-offset reduction folded in: each block redundantly
// sums bsum[0..blockIdx) (<=391 ints, L2-hot) — removes the scanpartial launch.
__global__ void writeoffs_kernel(const int* __restrict__ deg, const int* __restrict__ bsum,
                                 int* __restrict__ offs, int N) {
    __shared__ int buf[256];
    __shared__ int ws4[4];
    __shared__ int sboff;
    int t = threadIdx.x;
    int b = blockIdx.x;
    int partial = 0;
    for (int i = t; i < b; i += 256) partial += bsum[i];
#pragma unroll
    for (int off = 32; off > 0; off >>= 1) partial += __shfl_down(partial, off, 64);
    if ((t & 63) == 0) ws4[t >> 6] = partial;
    __syncthreads();
    if (t == 0) sboff = ws4[0] + ws4[1] + ws4[2] + ws4[3];
    __syncthreads();
    int i = b * 256 + t;
    int v = (i < N) ? deg[i] : 0;
    buf[t] = v;
    __syncthreads();
    for (int off = 1; off < 256; off <<= 1) {
        int u = (t >= off) ? buf[t - off] : 0;
        __syncthreads();
        buf[t] += u;
        __syncthreads();
    }
    int ex = buf[t] - v + sboff;
    if (i < N) offs[i] = ex;
    if (i == N - 1) offs[N] = ex + v;   // == E
}

// ATOMIC-FREE scatter into CSR-by-dst slots: pos = offs[dst] + rank.
// One packed 8B record per edge (halves every downstream csr read stream).
__global__ void fill_kernel(const int* __restrict__ src, const int* __restrict__ dst,
                            const int* __restrict__ rank, const int* __restrict__ offs,
                            unsigned long long* __restrict__ csr8, int E) {
    int e = blockIdx.x * blockDim.x + threadIdx.x;
    if (e >= E) return;
    int d = dst[e];
    int pos = offs[d] + rank[e];
    csr8[pos] = PK((unsigned int)src[e], (unsigned int)d, (unsigned int)e);
}

// nh = h / max(||h||,1e-12)  (separate kernel: r8's fused-norm coskey doubled
// per-thread load issue and cost +45us — reverted)
__global__ void rownorm_kernel(const float* __restrict__ h, float* __restrict__ nh, int N) {
    int i = blockIdx.x * blockDim.x + threadIdx.x;
    if (i >= N) return;
    const float4* hp = (const float4*)(h + (size_t)i * D_FEAT);
    float4 v[8];
    float ss = 0.f;
#pragma unroll
    for (int q = 0; q < 8; ++q) {
        v[q] = hp[q];
        ss += v[q].x * v[q].x + v[q].y * v[q].y + v[q].z * v[q].z + v[q].w * v[q].w;
    }
    float inv = 1.0f / fmaxf(sqrtf(ss), 1e-12f);
    float4* op = (float4*)(nh + (size_t)i * D_FEAT);
#pragma unroll
    for (int q = 0; q < 8; ++q) {
        float4 ov = v[q];
        ov.x *= inv; ov.y *= inv; ov.z *= inv; ov.w *= inv;
        op[q] = ov;
    }
}

// Redundant per-block 256-bin scan/select (reads the PREVIOUS kernel's
// histogram — visible via stream ordering, no fences). All 256 threads.
__device__ __forceinline__ unsigned long long scan_select(
        const unsigned int* __restrict__ hist,
        unsigned long long pfx_in, unsigned int k_in,
        unsigned int* k_out) {
    __shared__ unsigned int sbuf[256];
    __shared__ unsigned long long s_pfx;
    __shared__ unsigned int s_k;
    int t = threadIdx.x;
    unsigned int s = hist[t];
    sbuf[t] = s;
    __syncthreads();
    for (int off = 1; off < 256; off <<= 1) {
        unsigned int v = (t >= off) ? sbuf[t - off] : 0u;
        __syncthreads();
        sbuf[t] += v;
        __syncthreads();
    }
    unsigned int incl = sbuf[t];
    unsigned int excl = incl - s;
    if (excl < k_in && k_in <= incl) {          // exactly one thread wins
        s_pfx = (pfx_in << 8) | (unsigned long long)t;
        s_k = k_in - excl;
    }
    __syncthreads();
    if (k_out) *k_out = s_k;
    return s_pfx;
}

// edge-parallel cos keys, 2 CONSECUTIVE edges per thread (gather MLP);
// reads precomputed nh (r7 structure) via the packed 8B csr record.
// Per-edge dot order UNCHANGED (selection-critical rounding).
__global__ void coskey_kernel(const float* __restrict__ nh,
                              const unsigned long long* __restrict__ csr8,
                              unsigned long long* __restrict__ keys,
                              unsigned int* __restrict__ hist0, int E) {
    __shared__ unsigned int lh[4][256];
    int t = threadIdx.x;
#pragma unroll
    for (int w = 0; w < 4; ++w) lh[w][t] = 0u;
    __syncthreads();
    int wave = t >> 6;
    int p0 = (blockIdx.x * 256 + t) * 2;      // p0+1 < E by construction
    unsigned long long r0 = csr8[p0];
    unsigned long long r1 = csr8[p0 + 1];
    const float4* a0 = (const float4*)(nh + (size_t)PK_SRC(r0) * D_FEAT);
    const float4* b0 = (const float4*)(nh + (size_t)PK_DST(r0) * D_FEAT);
    const float4* a1 = (const float4*)(nh + (size_t)PK_SRC(r1) * D_FEAT);
    const float4* b1 = (const float4*)(nh + (size_t)PK_DST(r1) * D_FEAT);
    float s0 = 0.f, s1 = 0.f;
#pragma unroll
    for (int q = 0; q < 8; ++q) {
        float4 x0 = a0[q], y0 = b0[q];
        s0 += x0.x * y0.x + x0.y * y0.y + x0.z * y0.z + x0.w * y0.w;
        float4 x1 = a1[q], y1 = b1[q];
        s1 += x1.x * y1.x + x1.y * y1.y + x1.z * y1.z + x1.w * y1.w;
    }
    unsigned int u0 = __float_as_uint(s0);
    unsigned int so0 = (u0 & 0x80000000u) ? ~u0 : (u0 | 0x80000000u);
    unsigned long long k0 = ((unsigned long long)so0 << 32) | PK_EID(r0);
    unsigned int u1 = __float_as_uint(s1);
    unsigned int so1 = (u1 & 0x80000000u) ? ~u1 : (u1 | 0x80000000u);
    unsigned long long k1 = ((unsigned long long)so1 << 32) | PK_EID(r1);
    *(ulonglong2*)(keys + p0) = make_ulonglong2(k0, k1);
    atomicAdd(&lh[wave][(unsigned int)(k0 >> 56)], 1u);
    atomicAdd(&lh[wave][(unsigned int)(k1 >> 56)], 1u);
    __syncthreads();
    unsigned int tot = lh[0][t] + lh[1][t] + lh[2][t] + lh[3][t];
    if (tot) atomicAdd(&hist0[t], tot);
}

// compacting radix pass p (1..2). Redundant scan of hist_prev derives
// (prefix,k); block 0 persists it to st_out (read only by later kernels).
// NOTE: pass 2 must stay grid-wide — cos values are concentrated, the selected
// digit-0 bucket can hold ~250K keys (slice geometry caps survivors at 1600/block).
__global__ void histc_kernel(const unsigned long long* __restrict__ in,
                             const int* __restrict__ cnt_in,      // null => dense (pass 1)
                             unsigned long long* __restrict__ out,
                             int* __restrict__ cnt_out,
                             const SelState* __restrict__ st_in,  // null => {0, CUT_K}
                             SelState* __restrict__ st_out,
                             const unsigned int* __restrict__ hist_prev,
                             unsigned int* __restrict__ hist_cur, int pass) {
    __shared__ unsigned int lh[4][256];
    __shared__ unsigned int lcnt;
    int t = threadIdx.x, b = blockIdx.x;
#pragma unroll
    for (int w = 0; w < 4; ++w) lh[w][t] = 0u;
    if (t == 0) lcnt = 0u;

    unsigned long long pfx_in = st_in ? st_in->prefix : 0ull;
    unsigned int k_in = st_in ? st_in->k : (unsigned int)CUT_K;
    unsigned int k_cur;
    unsigned long long prefix = scan_select(hist_prev, pfx_in, k_in, &k_cur);
    if (b == 0 && t == 0) { st_out->prefix = prefix; st_out->k = k_cur; }
    __syncthreads();

    int n = cnt_in ? cnt_in[b] : HC_SLICE;
    const unsigned long long* sin = in + (size_t)b * HC_SLICE;
    unsigned long long* sout = out + (size_t)b * HC_SLICE;
    int wave = t >> 6;
    int fshift = 64 - 8 * pass;
    int dshift = 56 - 8 * pass;
    for (int i = t; i < n; i += 256) {
        unsigned long long key = sin[i];
        if ((key >> fshift) == prefix) {
            atomicAdd(&lh[wave][(unsigned int)((key >> dshift) & 0xFFull)], 1u);
            unsigned int slot = atomicAdd(&lcnt, 1u);   // LDS atomic, block-local
            sout[slot] = key;
        }
    }
    __syncthreads();
    if (t == 0) cnt_out[b] = (int)lcnt;
    unsigned int tot = lh[0][t] + lh[1][t] + lh[2][t] + lh[3][t];
    if (tot) atomicAdd(&hist_cur[t], tot);
}

// single-block tail: radix passes 3..7 + final select, one launch.
__global__ void tail_kernel(const unsigned long long* __restrict__ in_sl,
                            const int* __restrict__ cnt_in,
                            unsigned long long* __restrict__ dense,
                            const SelState* __restrict__ st2,
                            const unsigned int* __restrict__ hist2,
                            unsigned long long* __restrict__ kth_out) {
    __shared__ unsigned int lh[256];
    __shared__ unsigned int sbuf[256];
    __shared__ unsigned long long s_pfx;
    __shared__ unsigned int s_k;
    __shared__ unsigned int s_n;
    int t = threadIdx.x;

    unsigned long long pfx = st2->prefix;
    unsigned int k = st2->k;
    {   // select digit 2 from hist2 (global, written by pass 2)
        unsigned int s = hist2[t];
        sbuf[t] = s;
        __syncthreads();
        for (int off = 1; off < 256; off <<= 1) {
            unsigned int v = (t >= off) ? sbuf[t - off] : 0u;
            __syncthreads();
            sbuf[t] += v;
            __syncthreads();
        }
        unsigned int incl = sbuf[t], excl = incl - s;
        if (excl < k && k <= incl) { s_pfx = (pfx << 8) | (unsigned long long)t; s_k = k - excl; }
        __syncthreads();
        pfx = s_pfx; k = s_k;
        __syncthreads();
    }

    unsigned int n_in = 0;
    for (int pass = 3; pass < 8; ++pass) {
        lh[t] = 0u;
        if (t == 0) s_n = 0u;
        __syncthreads();
        int fshift = 64 - 8 * pass;
        int dshift = 56 - 8 * pass;
        unsigned long long* outp = dense + ((pass & 1) ? 0 : TAILCAP);
        if (pass == 3) {
            for (int b = t; b < HC_NB; b += 256) {
                int n = cnt_in[b];
                const unsigned long long* sl = in_sl + (size_t)b * HC_SLICE;
                for (int i = 0; i < n; ++i) {
                    unsigned long long key = sl[i];
                    if ((key >> fshift) == pfx) {
                        atomicAdd(&lh[(unsigned int)((key >> dshift) & 0xFFull)], 1u);
                        unsigned int slot = atomicAdd(&s_n, 1u);
                        if (slot < TAILCAP) outp[slot] = key;
                    }
                }
            }
        } else {
            const unsigned long long* inp = dense + ((pass & 1) ? TAILCAP : 0);
            for (unsigned int i = t; i < n_in; i += 256) {
                unsigned long long key = inp[i];
                if ((key >> fshift) == pfx) {
                    atomicAdd(&lh[(unsigned int)((key >> dshift) & 0xFFull)], 1u);
                    unsigned int slot = atomicAdd(&s_n, 1u);
                    if (slot < TAILCAP) outp[slot] = key;
                }
            }
        }
        __syncthreads();
        n_in = s_n;
        unsigned int s = lh[t];
        sbuf[t] = s;
        __syncthreads();
        for (int off = 1; off < 256; off <<= 1) {
            unsigned int v = (t >= off) ? sbuf[t - off] : 0u;
            __syncthreads();
            sbuf[t] += v;
            __syncthreads();
        }
        unsigned int incl = sbuf[t], excl = incl - s;
        if (excl < k && k <= incl) { s_pfx = (pfx << 8) | (unsigned long long)t; s_k = k - excl; }
        __syncthreads();
        pfx = s_pfx; k = s_k;
        __syncthreads();
    }
    if (t == 0) *kth_out = pfx;    // full 64-bit kth key
}

// pull aggregation: one 32-lane group per node walks its CSR segment.
// Gathers RAW h * nrm[src] inline (bit-identical to staged form; nrm is 400KB,
// L2-resident). Reads the packed 8B csr record. FUSE_FC: hop-2 applies W via LDS.
template<bool FUSE_FC>
__global__ void aggregate_csr_kernel(const float* __restrict__ h_in, float* __restrict__ h_out,
                                     const int* __restrict__ offs,
                                     const unsigned long long* __restrict__ csr8,
                                     const unsigned long long* __restrict__ keys,
                                     const unsigned long long* __restrict__ kth_in,
                                     const float* __restrict__ nrm,
                                     const float* __restrict__ W, int N) {
    __shared__ float Ws[32][33];
    __shared__ float hrow[8][33];
    int t = threadIdx.x;
    if (FUSE_FC) {
        for (int i = t; i < 1024; i += 256) Ws[i >> 5][i & 31] = W[i];  // Ws[o][j]
        __syncthreads();
    }
    unsigned long long kth = *kth_in;
    int g = blockIdx.x * 8 + (t >> 5);
    int j = t & 31;
    if (!FUSE_FC && g >= N) return;    // grid is exact; guard kept for safety
    int lo = offs[g], hi = offs[g + 1];
    float acc = 0.f;
    int p = lo;
    for (; p + 8 <= hi; p += 8) {
        unsigned long long kk[8];
        unsigned int ss[8];
#pragma unroll
        for (int u = 0; u < 8; ++u) { kk[u] = keys[p + u]; ss[u] = PK_SRC(csr8[p + u]); }
        float vv[8];
#pragma unroll
        for (int u = 0; u < 8; ++u) vv[u] = h_in[(size_t)ss[u] * D_FEAT + j] * nrm[ss[u]];
#pragma unroll
        for (int u = 0; u < 8; ++u) acc += (kk[u] > kth) ? vv[u] : 0.f;  // same seq FP order
    }
    for (; p < hi; ++p) {
        if (keys[p] > kth) {
            unsigned int s = PK_SRC(csr8[p]);
            acc += h_in[(size_t)s * D_FEAT + j] * nrm[s];
        }
    }
    float val = acc * nrm[g];
    if (!FUSE_FC) {
        h_out[(size_t)g * D_FEAT + j] = val;
        return;
    }
    hrow[t >> 5][j] = val;
    __syncthreads();
    float oacc = 0.f;
#pragma unroll
    for (int q = 0; q < 32; ++q) oacc += hrow[t >> 5][q] * Ws[j][q];   // lane j == out feat
    h_out[(size_t)g * D_FEAT + j] = oacc;
}

extern "C" void kernel_launch(void* const* d_in, const int* in_sizes, int n_in,
                              void* d_out, int out_size, void* d_ws, size_t ws_size,
                              hipStream_t stream) {
    const float* features = (const float*)d_in[0];
    const float* W        = (const float*)d_in[1];
    const int*   src      = (const int*)d_in[2];
    const int*   dst      = (const int*)d_in[3];
    float*       out      = (float*)d_out;

    char* ws = (char*)d_ws;
    size_t o = 0;
    auto take = [&](size_t bytes) -> char* {
        char* p = ws + o;
        o += (bytes + 255) & ~(size_t)255;
        return p;
    };
    int*                deg     = (int*)take((size_t)N_NODES * 4);
    float*              nrm     = (float*)take((size_t)N_NODES * 4);
    int*                offs    = (int*)take((size_t)(N_NODES + 1) * 4);
    int*                rank    = (int*)take((size_t)N_EDGES * 4);
    unsigned long long* csr8    = (unsigned long long*)take((size_t)N_EDGES * 8);
    float*              hA      = (float*)take((size_t)N_NODES * D_FEAT * 4);
    float*              nh      = (float*)take((size_t)N_NODES * D_FEAT * 4);
    unsigned long long* keys    = (unsigned long long*)take((size_t)N_EDGES * 8);
    unsigned long long* candA   = (unsigned long long*)take((size_t)HC_NB * HC_SLICE * 8);
    unsigned long long* candB   = (unsigned long long*)take((size_t)HC_NB * HC_SLICE * 8);
    unsigned int*       hist    = (unsigned int*)take((size_t)16 * 256 * 4); // per-pass bins
    SelState*           stArr   = (SelState*)take((size_t)16 * sizeof(SelState));
    unsigned long long* kthbuf  = (unsigned long long*)take(256);
    int*                bsum    = (int*)take((size_t)SCAN_NB * 4);
    int*                cnt_a   = (int*)take((size_t)HC_NB * 4);
    int*                cnt_b   = (int*)take((size_t)HC_NB * 4);

    hipMemsetAsync(deg, 0, (size_t)N_NODES * 4, stream);
    hipMemsetAsync(hist, 0, (size_t)16 * 256 * 4, stream);

    deg_kernel<<<(N_EDGES + 255) / 256, 256, 0, stream>>>(dst, deg, rank, N_EDGES);
    blocksum_kernel<<<SCAN_NB, 256, 0, stream>>>(deg, bsum, nrm, N_NODES);
    writeoffs_kernel<<<SCAN_NB, 256, 0, stream>>>(deg, bsum, offs, N_NODES);
    fill_kernel<<<(N_EDGES + 255) / 256, 256, 0, stream>>>(src, dst, rank, offs, csr8, N_EDGES);

    const float* hin = features;
    for (int hop = 0; hop < 2; ++hop) {
        unsigned int* hh = hist + (size_t)hop * 8 * 256;   // per-pass histograms
        SelState*     hst = stArr + (size_t)hop * 8;       // slots [1..2] used
        rownorm_kernel<<<(N_NODES + 255) / 256, 256, 0, stream>>>(hin, nh, N_NODES);
        coskey_kernel<<<COSKEY_NB, 256, 0, stream>>>(nh, csr8, keys, hh, N_EDGES);
        // pass 1: dense keys -> candA slices
        histc_kernel<<<HC_NB, 256, 0, stream>>>(keys, nullptr, candA, cnt_a,
                                                nullptr, hst + 1,
                                                hh + 0 * 256, hh + 1 * 256, 1);
        // pass 2: candA slices -> candB slices
        histc_kernel<<<HC_NB, 256, 0, stream>>>(candA, cnt_a, candB, cnt_b,
                                                hst + 1, hst + 2,
                                                hh + 1 * 256, hh + 2 * 256, 2);
        // passes 3..7 + final select in ONE single-block launch
        tail_kernel<<<1, 256, 0, stream>>>(candB, cnt_b, candA,
                                           hst + 2, hh + 2 * 256, kthbuf + hop);
        if (hop == 0) {
            aggregate_csr_kernel<false><<<(N_NODES + 7) / 8, 256, 0, stream>>>(
                hin, hA, offs, csr8, keys, kthbuf + hop, nrm, nullptr, N_NODES);
            hin = hA;
        } else {
            aggregate_csr_kernel<true><<<(N_NODES + 7) / 8, 256, 0, stream>>>(
                hin, out, offs, csr8, keys, kthbuf + hop, nrm, W, N_NODES);
        }
    }
}